// Round 3
// baseline (893.076 us; speedup 1.0000x reference)
//
#include <hip/hip_runtime.h>

// Seq2Seq LSTM (enc 512 + dec 256 steps), H=50, B=2048, in/out dim 1.
//
// Round-15: BARRIER-FREE single-wave blocks. r12/r13/r14 all measured
// ~1640 cyc/step while accountable chain is ~550 -> the ~1100-cyc stall is
// pinned on the cross-wave exchange (lgkmcnt(0)+s_barrier x768 + skew +
// decoder store drains). This version: 1 wave = 1 block = 4 batches,
// computing ALL 50 units itself. No __syncthreads anywhere.
//  - Split-on-rows: A row m = b*4 + s*2 + d (s = bf16 split of h, d = dup).
//    MFMA x{w0,w1} gives the FULL (h0+h1)(w0+w1) product; per-tile combine
//    is acc[0]+acc[2] in-lane. 64 MFMA/step for 4 batches (vs 96) and
//    better numerics than the old 3-term split.
//  - 16 tiles = 4 gates x 4 unit-groups(16,16,16,2+pad): gates of unit u
//    share a lane-col across tiles -> i,f,g,o combine fully in-lane.
//  - h exchange = wave-local LDS transpose (in-order DS pipe, no barrier).
//  - decoder y: in-lane fc dot + 16-lane shfl_xor reduce; ys staged in LDS,
//    one coalesced write at the end (no in-loop global stores/vmcnt drain).
//  - weights resident in ~256 VGPRs (launch_bounds(64,1), 1 wave/SIMD).
//
// Verified conventions (r10-r13): A[m=lane&15][k=(lane>>4)*8+j],
// B[n=lane&15][k=(lane>>4)*8+j], D col=lane&15, row=(lane>>4)*4+reg.
// L2E folded into weights/bias (gate g doubled -> tanh via sigm).

#define HID 50
#define SEQ 512
#define TGT 256
#define MB  4
#define NT  16
#define L2E 1.44269504088896341f

typedef __attribute__((ext_vector_type(8))) short short8;
typedef __attribute__((ext_vector_type(4))) float f32x4;

__device__ __forceinline__ unsigned short f2bf(float f) {   // RNE fp32->bf16
    unsigned u = __float_as_uint(f);
    return (unsigned short)((u + 0x7fffu + ((u >> 16) & 1u)) >> 16);
}
__device__ __forceinline__ float bf2f(unsigned short b) {
    return __uint_as_float(((unsigned)b) << 16);
}
__device__ __forceinline__ float sigm2(float a) {   // a pre-scaled by L2E
    return __builtin_amdgcn_rcpf(1.0f + __builtin_amdgcn_exp2f(-a));
}
__device__ __forceinline__ float tanhc(float c) {   // c in linear domain
    return fmaf(2.0f,
        __builtin_amdgcn_rcpf(1.0f + __builtin_amdgcn_exp2f(-2.0f * L2E * c)),
        -1.0f);
}

#define MFMA(A, B, C) __builtin_amdgcn_mfma_f32_16x16x32_bf16((A), (B), (C), 0, 0, 0)

// One step: read h from buf IB, compute, write h' to buf OB. XV = x input.
// Defines gate values into cc[]/hv[] (function scope).
#define GSTEP(XV, IB, OB)                                                   \
    {                                                                       \
        const short* hp_ = &hs[IB][as][ab][0];                              \
        short8 a0 = *(const short8*)(hp_ + kg * 8);        /* k 0..31  */   \
        short8 a1 = *(const short8*)(hp_ + 32 + kg * 8);   /* k 32..63 */   \
        float xv_ = (XV);                                                   \
        f32x4 acc[NT];                                                      \
        _Pragma("unroll")                                                   \
        for (int j = 0; j < NT; ++j) {                                      \
            f32x4 z = {0.0f, 0.0f, 0.0f, 0.0f};                             \
            z = MFMA(a0, Bw[j][0][0], z);                                   \
            z = MFMA(a0, Bw[j][0][1], z);                                   \
            z = MFMA(a1, Bw[j][1][0], z);                                   \
            z = MFMA(a1, Bw[j][1][1], z);                                   \
            acc[j] = z;                                                     \
        }                                                                   \
        short* wp_ = &hs[OB][0][0][0];                                      \
        _Pragma("unroll")                                                   \
        for (int ug = 0; ug < 4; ++ug) {                                    \
            float sI = acc[0 * 4 + ug][0] + acc[0 * 4 + ug][2]              \
                     + fmaf(wx[0 * 4 + ug], xv_, bb[0 * 4 + ug]);           \
            float sF = acc[1 * 4 + ug][0] + acc[1 * 4 + ug][2]              \
                     + fmaf(wx[1 * 4 + ug], xv_, bb[1 * 4 + ug]);           \
            float sG = acc[2 * 4 + ug][0] + acc[2 * 4 + ug][2]              \
                     + fmaf(wx[2 * 4 + ug], xv_, bb[2 * 4 + ug]);           \
            float sO = acc[3 * 4 + ug][0] + acc[3 * 4 + ug][2]              \
                     + fmaf(wx[3 * 4 + ug], xv_, bb[3 * 4 + ug]);           \
            float vi = sigm2(sI);                                           \
            float vf = sigm2(sF);                                           \
            float vg = fmaf(2.0f, sigm2(sG), -1.0f);                        \
            float vo = sigm2(sO);                                           \
            cc[ug] = fmaf(vf, cc[ug], vi * vg);                             \
            hv[ug] = vo * tanhc(cc[ug]);                                    \
            unsigned short q0 = f2bf(hv[ug]);                               \
            unsigned short q1 = f2bf(hv[ug] - bf2f(q0));                    \
            wp_[wofs + ug * 16]       = (short)q0;   /* split0 */           \
            wp_[wofs + ug * 16 + 288] = (short)q1;   /* split1 */           \
        }                                                                   \
    }

// Decoder step: GSTEP + in-lane fc dot + 16-lane butterfly; y -> ys, xc.
#define DSTEP(T, IB, OB)                                                    \
    {                                                                       \
        GSTEP(xc, IB, OB)                                                   \
        float p = fmaf(fcw0, hv[0],                                         \
                  fmaf(fcw1, hv[1],                                         \
                  fmaf(fcw2, hv[2], fcw3 * hv[3])));                        \
        p += __shfl_xor(p, 1);                                              \
        p += __shfl_xor(p, 2);                                              \
        p += __shfl_xor(p, 4);                                              \
        p += __shfl_xor(p, 8);                                              \
        float y = p + fb;                                                   \
        if (c == 0) ys[kg][T] = y;                                          \
        xc = y;                                                             \
    }

extern "C" __global__ void __launch_bounds__(64, 1)
seq2seq_kernel(const float* __restrict__ src,
               const float* __restrict__ eWih, const float* __restrict__ eWhh,
               const float* __restrict__ eBih, const float* __restrict__ eBhh,
               const float* __restrict__ dWih, const float* __restrict__ dWhh,
               const float* __restrict__ dBih, const float* __restrict__ dBhh,
               const float* __restrict__ fcW, const float* __restrict__ fcB,
               float* __restrict__ out) {
    const int lane = threadIdx.x & 63;
    const int c    = lane & 15;          // lane col: D output col / A row m
    const int kg   = lane >> 4;          // D batch group AND A/B k-octet
    const int ab   = c >> 2;             // A-source batch  = m>>2
    const int as   = (c >> 1) & 1;       // A-source split  = (m>>1)&1
    const int b0   = blockIdx.x * MB;
    const int wofs = kg * 72 + c;        // h-write base (shorts, split0)

    // hs[buf][split][batch][72 units(50 used, 144B rows keep 16B align)]
    __shared__ __align__(16) short hs[2][2][MB][72];
    __shared__ __align__(16) float srcT[SEQ * MB];   // [t][4 batches]
    __shared__ __align__(16) float ys[MB][TGT];      // decoder outputs

    for (int i = lane; i < 2 * 2 * MB * 72 / 2; i += 64) ((int*)hs)[i] = 0;
    for (int i = lane; i < SEQ * MB; i += 64) {
        int e = i >> 9, t = i & 511;                 // coalesced in t
        srcT[t * MB + e] = src[(size_t)(b0 + e) * SEQ + t];
    }
    // single wave: in-order DS pipe, no barrier needed

    short8 Bw[NT][2][2];                 // [tile][kt][wsplit] weight frags
    float wx[NT], bb[NT];
    float cc[4] = {0.0f, 0.0f, 0.0f, 0.0f};
    float hv[4];

    auto loadW = [&](const float* Wih, const float* Whh,
                     const float* Bih, const float* Bhh) {
#pragma unroll
        for (int j = 0; j < NT; ++j) {
            const int g  = j >> 2, ug = j & 3;       // tile = (gate, ugroup)
            const int u  = ug * 16 + c;              // this col's unit
            const bool uv = (u < HID);
            const float sc = (g == 2) ? 2.0f * L2E : L2E;   // tanh fold
            const int row = g * HID + (uv ? u : 0);  // PyTorch g*50+u
            wx[j] = uv ? Wih[row] * sc : 0.0f;
            bb[j] = uv ? (Bih[row] + Bhh[row]) * sc : 0.0f;
#pragma unroll
            for (int kt = 0; kt < 2; ++kt) {
                short8 s0, s1;
#pragma unroll
                for (int jj = 0; jj < 8; ++jj) {
                    int kk = kt * 32 + kg * 8 + jj;
                    float wv = (uv && kk < HID)
                             ? Whh[(size_t)row * HID + kk] * sc : 0.0f;
                    unsigned short h0 = f2bf(wv);
                    s0[jj] = (short)h0;
                    s1[jj] = (short)f2bf(wv - bf2f(h0));
                }
                Bw[j][kt][0] = s0; Bw[j][kt][1] = s1;
            }
        }
    };

    // ---------------- encoder: 512 steps (x2 unroll, h dbuf) -------------
    loadW(eWih, eWhh, eBih, eBhh);
    for (int t = 0; t < SEQ; t += 2) {
        { GSTEP(srcT[t * MB + kg], 0, 1) }
        { GSTEP(srcT[(t + 1) * MB + kg], 1, 0) }
    }
    // h(512) in buf 0; cc persists in registers

    // ---------------- decoder: 256 steps (x2 unroll) ---------------------
    loadW(dWih, dWhh, dBih, dBhh);
    const float fcw0 = fcW[c];
    const float fcw1 = fcW[16 + c];
    const float fcw2 = fcW[32 + c];
    const float fcw3 = (48 + c < HID) ? fcW[48 + c] : 0.0f;
    const float fb   = fcB[0];
    float xc = 0.0f;                     // decoder_input = zeros
    for (int t = 0; t < TGT; t += 2) {
        DSTEP(t,     0, 1)
        DSTEP(t + 1, 1, 0)
    }

    // coalesced output write
    for (int i = lane; i < MB * TGT; i += 64) {
        int b = i >> 8, t = i & 255;
        out[(size_t)(b0 + b) * TGT + t] = ys[b][t];
    }
}

extern "C" void kernel_launch(void* const* d_in, const int* in_sizes, int n_in,
                              void* d_out, int out_size, void* d_ws, size_t ws_size,
                              hipStream_t stream) {
    const float* src  = (const float*)d_in[0];
    const float* eWih = (const float*)d_in[1];
    const float* eWhh = (const float*)d_in[2];
    const float* eBih = (const float*)d_in[3];
    const float* eBhh = (const float*)d_in[4];
    const float* dWih = (const float*)d_in[5];
    const float* dWhh = (const float*)d_in[6];
    const float* dBih = (const float*)d_in[7];
    const float* dBhh = (const float*)d_in[8];
    const float* fcW  = (const float*)d_in[9];
    const float* fcB  = (const float*)d_in[10];
    float* out = (float*)d_out;

    const int B = in_sizes[0] / SEQ;     // 2048
    seq2seq_kernel<<<B / MB, 64, 0, stream>>>(src, eWih, eWhh, eBih, eBhh,
                                              dWih, dWhh, dBih, dBhh,
                                              fcW, fcB, out);
}

// Round 4
// 664.510 us; speedup vs baseline: 1.3440x; 1.3440x over previous
//
#include <hip/hip_runtime.h>

// Seq2Seq LSTM (enc 512 + dec 256 steps), H=50, B=2048, in/out dim 1.
//
// Round-16: TWO independent 4-batch chains per block ("sets"), interleaved
// in the same 4 waves. Rationale: wall = 768 x single-block serial chain
// (all blocks co-resident in every config; r12/r13 identical at ~1640
// cyc/step, r14 chain-split neutral, r15 single-wave worse). The ~1100-cyc
// exposed latency per step (LDS round-trip + trans chains + barrier drain)
// can only be filled by a SECOND independent chain in the same wave:
// GCOREX(set0); GCOREX(set1); one barrier. Stall amortizes over 2 steps.
// Weights shared between sets (+0 VGPR); acc transient doubles (~+64).
//
// Fragments (verified r10-r14, absmax 4.9e-4):
//   A[m=lane&15][k=kg*8+j]  B[n=nl][k=kt*32+kg*8+j]  D row=4*kg+r, col=nl.
// A-row m carries batch m>>2 (duplication) so every lane's gates live in
// REG 0 of each accumulator. L2E folded into weights/bias (gate g doubled
// -> tanh via sigm). Per gate: two depth-3 MFMA chains (kt0/kt1) + scalar
// combine (r14).

#define HID 50
#define SEQ 512
#define TGT 256
#define MB  8                    // 2 sets x 4 batches
#define L2E 1.44269504088896341f

typedef __attribute__((ext_vector_type(8))) short short8;
typedef __attribute__((ext_vector_type(4))) float f32x4;

__device__ __forceinline__ unsigned short f2bf(float f) {   // RNE fp32->bf16
    unsigned u = __float_as_uint(f);
    return (unsigned short)((u + 0x7fffu + ((u >> 16) & 1u)) >> 16);
}
__device__ __forceinline__ float bf2f(unsigned short b) {
    return __uint_as_float(((unsigned)b) << 16);
}
__device__ __forceinline__ float sigm2(float a) {   // a pre-scaled by L2E
    return __builtin_amdgcn_rcpf(1.0f + __builtin_amdgcn_exp2f(-a));
}
__device__ __forceinline__ float tanhc(float c) {   // c in linear domain
    return fmaf(2.0f,
        __builtin_amdgcn_rcpf(1.0f + __builtin_amdgcn_exp2f(-2.0f * L2E * c)),
        -1.0f);
}

#define MFMA(A, B, C) __builtin_amdgcn_mfma_f32_16x16x32_bf16((A), (B), (C), 0, 0, 0)

// h layout: block (split s, k-tile kt, k-octet qg) = 4 batches x 8 k shorts.
#define HB(s, kt, qg) ((((s) * 2 + (kt)) * 4 + (qg)) * 32)
#define HFSZ (2 * 2 * 4 * 32)   // 512 shorts per buffer

// One step of one set. XK = x scalar for batch kg (ignored if POSTX).
// POSTX=1: C-init = bias only; + wx*XC added post-MFMA (decoder feedback
// stays off the MFMA critical path). CC = cell reg, HV = output var name.
#define GCOREX(XK, POSTX, XC, CC, HV, HIN, HOUT)                       \
    {                                                                  \
        const short* hin_ = (HIN);                                     \
        short8 a00 = *(const short8*)(hin_ + HB(0, 0, kg) + bsel * 8); \
        short8 a10 = *(const short8*)(hin_ + HB(0, 1, kg) + bsel * 8); \
        short8 a01 = *(const short8*)(hin_ + HB(1, 0, kg) + bsel * 8); \
        short8 a11 = *(const short8*)(hin_ + HB(1, 1, kg) + bsel * 8); \
        float i0, i1, i2, i3;                                          \
        if (POSTX) {                                                   \
            i0 = bb[0]; i1 = bb[1]; i2 = bb[2]; i3 = bb[3];            \
        } else {                                                       \
            i0 = fmaf(wx[0], (XK), bb[0]);                             \
            i1 = fmaf(wx[1], (XK), bb[1]);                             \
            i2 = fmaf(wx[2], (XK), bb[2]);                             \
            i3 = fmaf(wx[3], (XK), bb[3]);                             \
        }                                                              \
        f32x4 cA0 = {i0, i0, i0, i0};                                  \
        f32x4 cA1 = {i1, i1, i1, i1};                                  \
        f32x4 cA2 = {i2, i2, i2, i2};                                  \
        f32x4 cA3 = {i3, i3, i3, i3};                                  \
        f32x4 cB0 = {0.0f, 0.0f, 0.0f, 0.0f};                          \
        f32x4 cB1 = cB0, cB2 = cB0, cB3 = cB0;                         \
        cA0 = MFMA(a00, Bf[0][0][0], cA0);                             \
        cB0 = MFMA(a10, Bf[0][1][0], cB0);                             \
        cA1 = MFMA(a00, Bf[1][0][0], cA1);                             \
        cB1 = MFMA(a10, Bf[1][1][0], cB1);                             \
        cA2 = MFMA(a00, Bf[2][0][0], cA2);                             \
        cB2 = MFMA(a10, Bf[2][1][0], cB2);                             \
        cA3 = MFMA(a00, Bf[3][0][0], cA3);                             \
        cB3 = MFMA(a10, Bf[3][1][0], cB3);                             \
        cA0 = MFMA(a00, Bf[0][0][1], cA0);                             \
        cB0 = MFMA(a10, Bf[0][1][1], cB0);                             \
        cA1 = MFMA(a00, Bf[1][0][1], cA1);                             \
        cB1 = MFMA(a10, Bf[1][1][1], cB1);                             \
        cA2 = MFMA(a00, Bf[2][0][1], cA2);                             \
        cB2 = MFMA(a10, Bf[2][1][1], cB2);                             \
        cA3 = MFMA(a00, Bf[3][0][1], cA3);                             \
        cB3 = MFMA(a10, Bf[3][1][1], cB3);                             \
        cA0 = MFMA(a01, Bf[0][0][0], cA0);                             \
        cB0 = MFMA(a11, Bf[0][1][0], cB0);                             \
        cA1 = MFMA(a01, Bf[1][0][0], cA1);                             \
        cB1 = MFMA(a11, Bf[1][1][0], cB1);                             \
        cA2 = MFMA(a01, Bf[2][0][0], cA2);                             \
        cB2 = MFMA(a11, Bf[2][1][0], cB2);                             \
        cA3 = MFMA(a01, Bf[3][0][0], cA3);                             \
        cB3 = MFMA(a11, Bf[3][1][0], cB3);                             \
        float s0 = cA0[0] + cB0[0];                                    \
        float s1 = cA1[0] + cB1[0];                                    \
        float s2 = cA2[0] + cB2[0];                                    \
        float s3 = cA3[0] + cB3[0];                                    \
        if (POSTX) {                                                   \
            s0 = fmaf(wx[0], (XC), s0);                                \
            s1 = fmaf(wx[1], (XC), s1);                                \
            s2 = fmaf(wx[2], (XC), s2);                                \
            s3 = fmaf(wx[3], (XC), s3);                                \
        }                                                              \
        float vi = sigm2(s0);                                          \
        float vf = sigm2(s1);                                          \
        float vg = fmaf(2.0f, sigm2(s2), -1.0f);                       \
        float vo = sigm2(s3);                                          \
        (CC) = fmaf(vf, (CC), vi * vg);                                \
        (HV) = vo * tanhc(CC);                                         \
        unsigned short q0 = f2bf(HV);                                  \
        unsigned short q1 = f2bf((HV) - bf2f(q0));                     \
        short* ho_ = (HOUT);                                           \
        ho_[wr0] = (short)q0;                                          \
        ho_[wr1] = (short)q1;                                          \
    }

// Decoder interval: both sets' GCOREX + fc butterflies; ONE barrier; y
// rebuild; coalesced-enough out writes (8 floats/step from wave 0).
#define DSTEP2(T, HIN0, HOUT0, HIN1, HOUT1, PB0, PB1)                  \
    {                                                                  \
        GCOREX(0.0f, 1, xc0, cc0, hv0, HIN0, HOUT0)                    \
        GCOREX(0.0f, 1, xc1, cc1, hv1, HIN1, HOUT1)                    \
        float p0 = fcw * hv0;                                          \
        float p1 = fcw * hv1;                                          \
        p0 += __shfl_xor(p0, 1, 64);                                   \
        p1 += __shfl_xor(p1, 1, 64);                                   \
        p0 += __shfl_xor(p0, 2, 64);                                   \
        p1 += __shfl_xor(p1, 2, 64);                                   \
        p0 += __shfl_xor(p0, 4, 64);                                   \
        p1 += __shfl_xor(p1, 4, 64);                                   \
        p0 += __shfl_xor(p0, 8, 64);                                   \
        p1 += __shfl_xor(p1, 8, 64);                                   \
        if (nl == 0) { (PB0)[kg * 4 + w] = p0; (PB1)[kg * 4 + w] = p1; }\
        __syncthreads();                                               \
        f32x4 u0 = *(const f32x4*)&(PB0)[kg * 4];                      \
        f32x4 u1 = *(const f32x4*)&(PB1)[kg * 4];                      \
        float y0 = u0[0] + u0[1] + u0[2] + u0[3] + fb;                 \
        float y1 = u1[0] + u1[1] + u1[2] + u1[3] + fb;                 \
        if (w == 0 && nl == 0) {                                       \
            out[(size_t)(b0 + kg) * TGT + (T)]     = y0;               \
            out[(size_t)(b0 + 4 + kg) * TGT + (T)] = y1;               \
        }                                                              \
        xc0 = y0; xc1 = y1;                                            \
    }

extern "C" __global__ void __launch_bounds__(256, 1)
seq2seq_kernel(const float* __restrict__ src,
               const float* __restrict__ eWih, const float* __restrict__ eWhh,
               const float* __restrict__ eBih, const float* __restrict__ eBhh,
               const float* __restrict__ dWih, const float* __restrict__ dWhh,
               const float* __restrict__ dBih, const float* __restrict__ dBhh,
               const float* __restrict__ fcW, const float* __restrict__ fcB,
               float* __restrict__ out) {
    const int tid  = threadIdx.x;        // 0..255
    const int lane = tid & 63;
    const int w    = tid >> 6;           // wave 0..3 = unit tile
    const int nl   = lane & 15;          // n-col within tile
    const int kg   = lane >> 4;          // k-octet; ALSO this lane's batch
    const int bsel = nl >> 2;            // A-row m -> batch m>>2
    const int un   = 16 * w + nl;        // this lane's unit
    const int b0   = blockIdx.x * MB;
    const int ukt  = un >> 5, uqg = (un >> 3) & 3, uj = un & 7;
    const int wr0  = HB(0, ukt, uqg) + kg * 8 + uj;   // h split-0 write
    const int wr1  = HB(1, ukt, uqg) + kg * 8 + uj;   // h split-1 write

    // per-set h double-buffers
    __shared__ __align__(16) short hA0[HFSZ], hB0[HFSZ];
    __shared__ __align__(16) short hA1[HFSZ], hB1[HFSZ];
    __shared__ __align__(16) float srcT[SEQ * MB];    // [t][8 batches]
    __shared__ __align__(16) float pbA0[16], pbB0[16], pbA1[16], pbB1[16];

    for (int i = tid; i < HFSZ; i += 256) {
        hA0[i] = 0; hB0[i] = 0; hA1[i] = 0; hB1[i] = 0;
    }
    for (int i = tid; i < SEQ * MB; i += 256) {
        int e = i >> 9, t = i & 511;                  // coalesced in t
        srcT[t * MB + e] = src[(size_t)(b0 + e) * SEQ + t];
    }

    short8 Bf[4][2][2];                  // [gate][kt][split] — shared by sets
    float bb[4], wx[4];
    float cc0 = 0.0f, cc1 = 0.0f;        // cells (set, batch kg, unit un)
    float hv0, hv1;
    float xc0 = 0.0f, xc1 = 0.0f;        // decoder feedback

    auto loadW = [&](const float* Wih, const float* Whh,
                     const float* Bih, const float* Bhh) {
#pragma unroll
        for (int g = 0; g < 4; ++g) {
            const float sc = (g == 2) ? 2.0f * L2E : L2E;  // tanh fold
            const bool nv  = (un < HID);
            const int row  = g * HID + (nv ? un : 0);      // PyTorch g*50+u
            bb[g] = nv ? (Bih[row] + Bhh[row]) * sc : 0.0f;
            wx[g] = nv ? Wih[row] * sc : 0.0f;
#pragma unroll
            for (int kt = 0; kt < 2; ++kt) {
                short8 s0, s1;
#pragma unroll
                for (int j = 0; j < 8; ++j) {
                    int kk = kt * 32 + kg * 8 + j;
                    float wv = (nv && kk < HID)
                             ? Whh[(size_t)row * HID + kk] * sc : 0.0f;
                    unsigned short h0 = f2bf(wv);
                    s0[j] = (short)h0; s1[j] = (short)f2bf(wv - bf2f(h0));
                }
                Bf[g][kt][0] = s0; Bf[g][kt][1] = s1;
            }
        }
    };

    // ---------------- encoder: 512 steps (x2 unroll, 1 barrier/step) -----
    loadW(eWih, eWhh, eBih, eBhh);
    __syncthreads();                     // h zero + srcT staged
    for (int t = 0; t < SEQ; t += 2) {
        GCOREX(srcT[t * MB + kg],     0, 0.0f, cc0, hv0, hA0, hB0)
        GCOREX(srcT[t * MB + 4 + kg], 0, 0.0f, cc1, hv1, hA1, hB1)
        __syncthreads();
        GCOREX(srcT[(t + 1) * MB + kg],     0, 0.0f, cc0, hv0, hB0, hA0)
        GCOREX(srcT[(t + 1) * MB + 4 + kg], 0, 0.0f, cc1, hv1, hB1, hA1)
        __syncthreads();
    }
    // state in hA0 / hA1

    // ---------------- decoder: 256 steps (x2 unroll) ---------------------
    loadW(dWih, dWhh, dBih, dBhh);
    const float fcw = (un < HID) ? fcW[un] : 0.0f;
    const float fb  = fcB[0];
    for (int t = 0; t < TGT; t += 2) {
        DSTEP2(t,     hA0, hB0, hA1, hB1, pbA0, pbA1)
        DSTEP2(t + 1, hB0, hA0, hB1, hA1, pbB0, pbB1)
    }
}

extern "C" void kernel_launch(void* const* d_in, const int* in_sizes, int n_in,
                              void* d_out, int out_size, void* d_ws, size_t ws_size,
                              hipStream_t stream) {
    const float* src  = (const float*)d_in[0];
    const float* eWih = (const float*)d_in[1];
    const float* eWhh = (const float*)d_in[2];
    const float* eBih = (const float*)d_in[3];
    const float* eBhh = (const float*)d_in[4];
    const float* dWih = (const float*)d_in[5];
    const float* dWhh = (const float*)d_in[6];
    const float* dBih = (const float*)d_in[7];
    const float* dBhh = (const float*)d_in[8];
    const float* fcW  = (const float*)d_in[9];
    const float* fcB  = (const float*)d_in[10];
    float* out = (float*)d_out;

    const int B = in_sizes[0] / SEQ;     // 2048
    seq2seq_kernel<<<B / MB, 256, 0, stream>>>(src, eWih, eWhh, eBih, eBhh,
                                               dWih, dWhh, dBih, dBhh,
                                               fcW, fcB, out);
}

// Round 5
// 591.725 us; speedup vs baseline: 1.5093x; 1.1230x over previous
//
#include <hip/hip_runtime.h>

// Seq2Seq LSTM (enc 512 + dec 256 steps), H=50, B=2048, in/out dim 1.
//
// Round-17: barrier-free single-wave blocks (r15 structure) REPAIRED with
// fp16 MFMA. Evidence chain: r12-r16 show wall = 768 x single-step critical
// path (1640cy at r13); the ~1200cy non-issue component is cross-wave sync
// (lgkmcnt(0)+s_barrier+skew) + latency, unfillable by ILP (r16: second
// independent chain overlapped 0%). r15 removed the barrier but spilled
// (256 VGPR of double-split bf16 weights -> WRITE_SIZE 9MB). Fix:
//  - mfma_f32_16x16x32_f16, SINGLE-precision fp16 weights: rel 2^-11,
//    |W|<=0.14 -> gate err ~1e-4 (better than bf16-split's 4.9e-4 path).
//    Weights: 16 tiles x 2 kt x 4 VGPR = 128 (was 256). MFMA 32/step.
//  - h bf16-split replaced by fp16 h-split riding A-ROWS (free): row
//    m = b*4 + s*2 + d (b=batch, s=h-split, d=dup); combine acc[0]+acc[2].
//  - 1 wave = 1 block = 4 batches, all 50 units; NO __syncthreads anywhere.
//    h exchange = wave-local LDS round-trip (in-order DS pipe).
//  - decoder y-feedback added post-MFMA (shuffle chain hides under issue);
//    ys staged in LDS, one coalesced global write at the end.
//
// Fragment maps (verified r10-r15): A[m=lane&15][k=(lane>>4)*8+j],
// B[n=lane&15][k=kt*32+(lane>>4)*8+j], D col=lane&15, row=4*(lane>>4)+reg.
// L2E folded into weights/bias (gate g=2 doubled -> tanh via sigm).
// Units 50..63 self-maintain as zeros (w=b=0 -> vg=0 -> hv=0).

#define HID 50
#define SEQ 512
#define TGT 256
#define MB  4
#define NT  16                   // 4 gates x 4 unit-groups
#define UPAD 72                  // unit stride (144B, 16B-aligned)
#define L2E 1.44269504088896341f

typedef __attribute__((ext_vector_type(8))) _Float16 half8;
typedef __attribute__((ext_vector_type(4))) float f32x4;

__device__ __forceinline__ float sigm2(float a) {   // a pre-scaled by L2E
    return __builtin_amdgcn_rcpf(1.0f + __builtin_amdgcn_exp2f(-a));
}
__device__ __forceinline__ float tanhc(float c) {   // c in linear domain
    return fmaf(2.0f,
        __builtin_amdgcn_rcpf(1.0f + __builtin_amdgcn_exp2f(-2.0f * L2E * c)),
        -1.0f);
}

#define MFMA16(A, B, C) __builtin_amdgcn_mfma_f32_16x16x32_f16((A), (B), (C), 0, 0, 0)

// hs[buf][split][batch][UPAD units]; strides in halves:
#define HS_S (MB * UPAD)         // split stride = 288
#define HS_SZ (2 * HS_S)         // one buffer = 576 halves

// One step: read h from hs[IB], compute, write h' to hs[OB]. XV = x scalar
// for this lane's batch kg (post-added with bias after the combine, so the
// decoder feedback chain overlaps MFMA issue). Defines hv[4] / updates cc[4].
#define GSTEP(XV, IB, OB)                                                   \
    {                                                                       \
        const _Float16* hp_ = &hs[IB][as][ab][0];                           \
        half8 a0 = *(const half8*)(hp_ + kg * 8);        /* k 0..31  */     \
        half8 a1 = *(const half8*)(hp_ + 32 + kg * 8);   /* k 32..63 */     \
        float xv_ = (XV);                                                   \
        f32x4 acc[NT];                                                      \
        _Pragma("unroll")                                                   \
        for (int j = 0; j < NT; ++j) {                                      \
            f32x4 z = {0.0f, 0.0f, 0.0f, 0.0f};                             \
            z = MFMA16(a0, Bw[j][0], z);                                    \
            z = MFMA16(a1, Bw[j][1], z);                                    \
            acc[j] = z;                                                     \
        }                                                                   \
        _Float16* wp_ = &hs[OB][0][0][0];                                   \
        _Pragma("unroll")                                                   \
        for (int ug = 0; ug < 4; ++ug) {                                    \
            float sI = acc[0 * 4 + ug][0] + acc[0 * 4 + ug][2]              \
                     + fmaf(wx[0 * 4 + ug], xv_, bb[0 * 4 + ug]);           \
            float sF = acc[1 * 4 + ug][0] + acc[1 * 4 + ug][2]              \
                     + fmaf(wx[1 * 4 + ug], xv_, bb[1 * 4 + ug]);           \
            float sG = acc[2 * 4 + ug][0] + acc[2 * 4 + ug][2]              \
                     + fmaf(wx[2 * 4 + ug], xv_, bb[2 * 4 + ug]);           \
            float sO = acc[3 * 4 + ug][0] + acc[3 * 4 + ug][2]              \
                     + fmaf(wx[3 * 4 + ug], xv_, bb[3 * 4 + ug]);           \
            float vi = sigm2(sI);                                           \
            float vf = sigm2(sF);                                           \
            float vg = fmaf(2.0f, sigm2(sG), -1.0f);                        \
            float vo = sigm2(sO);                                           \
            cc[ug] = fmaf(vf, cc[ug], vi * vg);                             \
            hv[ug] = vo * tanhc(cc[ug]);                                    \
            _Float16 q0 = (_Float16)hv[ug];                                 \
            _Float16 q1 = (_Float16)(hv[ug] - (float)q0);                   \
            wp_[kg * UPAD + ug * 16 + c]        = q0;   /* split0 */        \
            wp_[HS_S + kg * UPAD + ug * 16 + c] = q1;   /* split1 */        \
        }                                                                   \
    }

// Decoder step: GSTEP + in-lane fc dot + 16-lane butterfly; y -> ys, xc.
#define DSTEP(T, IB, OB)                                                    \
    {                                                                       \
        GSTEP(xc, IB, OB)                                                   \
        float p = fmaf(fcw0, hv[0],                                         \
                  fmaf(fcw1, hv[1],                                         \
                  fmaf(fcw2, hv[2], fcw3 * hv[3])));                        \
        p += __shfl_xor(p, 1, 64);                                          \
        p += __shfl_xor(p, 2, 64);                                          \
        p += __shfl_xor(p, 4, 64);                                          \
        p += __shfl_xor(p, 8, 64);                                          \
        float y = p + fb;                                                   \
        if (c == 0) ys[kg][T] = y;                                          \
        xc = y;                                                             \
    }

extern "C" __global__ void __launch_bounds__(64, 1)
seq2seq_kernel(const float* __restrict__ src,
               const float* __restrict__ eWih, const float* __restrict__ eWhh,
               const float* __restrict__ eBih, const float* __restrict__ eBhh,
               const float* __restrict__ dWih, const float* __restrict__ dWhh,
               const float* __restrict__ dBih, const float* __restrict__ dBhh,
               const float* __restrict__ fcW, const float* __restrict__ fcB,
               float* __restrict__ out) {
    const int lane = threadIdx.x & 63;
    const int c    = lane & 15;          // D col: unit within ugroup; A row m
    const int kg   = lane >> 4;          // A/B k-octet AND D batch group
    const int ab   = c >> 2;             // A-row m -> source batch
    const int as   = (c >> 1) & 1;       // A-row m -> source h-split
    const int b0   = blockIdx.x * MB;

    __shared__ __align__(16) _Float16 hs[2][2][MB][UPAD];  // dbuf h splits
    __shared__ __align__(16) float srcT[SEQ * MB];         // [t][4 batches]
    __shared__ __align__(16) float ys[MB][TGT];            // decoder outputs

    for (int i = lane; i < 2 * HS_SZ / 2; i += 64) ((int*)hs)[i] = 0;
    for (int i = lane; i < SEQ * MB; i += 64) {
        int e = i >> 9, t = i & 511;                       // coalesced in t
        srcT[t * MB + e] = src[(size_t)(b0 + e) * SEQ + t];
    }
    // single wave: DS pipe is in-order; no barrier needed anywhere

    half8 Bw[NT][2];                     // [tile=(g*4+ug)][kt] fp16 weights
    float wx[NT], bb[NT];
    float cc[4] = {0.0f, 0.0f, 0.0f, 0.0f};
    float hv[4];

    auto loadW = [&](const float* Wih, const float* Whh,
                     const float* Bih, const float* Bhh) {
#pragma unroll
        for (int j = 0; j < NT; ++j) {
            const int g  = j >> 2, ug = j & 3;             // tile=(gate,ug)
            const int u  = ug * 16 + c;                    // this col's unit
            const bool uv = (u < HID);
            const float sc = (g == 2) ? 2.0f * L2E : L2E;  // tanh fold
            const int row = g * HID + (uv ? u : 0);        // PyTorch g*50+u
            wx[j] = uv ? Wih[row] * sc : 0.0f;
            bb[j] = uv ? (Bih[row] + Bhh[row]) * sc : 0.0f;
#pragma unroll
            for (int kt = 0; kt < 2; ++kt) {
                half8 s0;
#pragma unroll
                for (int jj = 0; jj < 8; ++jj) {
                    int kk = kt * 32 + kg * 8 + jj;
                    float wv = (uv && kk < HID)
                             ? Whh[(size_t)row * HID + kk] * sc : 0.0f;
                    s0[jj] = (_Float16)wv;
                }
                Bw[j][kt] = s0;
            }
        }
    };

    // ---------------- encoder: 512 steps (x2 unroll, h dbuf) -------------
    loadW(eWih, eWhh, eBih, eBhh);
    for (int t = 0; t < SEQ; t += 2) {
        { GSTEP(srcT[t * MB + kg], 0, 1) }
        { GSTEP(srcT[(t + 1) * MB + kg], 1, 0) }
    }
    // h(512) in buf 0; cc persists in registers

    // ---------------- decoder: 256 steps (x2 unroll) ---------------------
    loadW(dWih, dWhh, dBih, dBhh);
    const float fcw0 = fcW[c];
    const float fcw1 = fcW[16 + c];
    const float fcw2 = fcW[32 + c];
    const float fcw3 = (48 + c < HID) ? fcW[48 + c] : 0.0f;
    const float fb   = fcB[0];
    float xc = 0.0f;                     // decoder_input = zeros
    for (int t = 0; t < TGT; t += 2) {
        DSTEP(t,     0, 1)
        DSTEP(t + 1, 1, 0)
    }

    // coalesced output write
    for (int i = lane; i < MB * TGT; i += 64) {
        int b = i >> 8, t = i & 255;
        out[(size_t)(b0 + b) * TGT + t] = ys[b][t];
    }
}

extern "C" void kernel_launch(void* const* d_in, const int* in_sizes, int n_in,
                              void* d_out, int out_size, void* d_ws, size_t ws_size,
                              hipStream_t stream) {
    const float* src  = (const float*)d_in[0];
    const float* eWih = (const float*)d_in[1];
    const float* eWhh = (const float*)d_in[2];
    const float* eBih = (const float*)d_in[3];
    const float* eBhh = (const float*)d_in[4];
    const float* dWih = (const float*)d_in[5];
    const float* dWhh = (const float*)d_in[6];
    const float* dBih = (const float*)d_in[7];
    const float* dBhh = (const float*)d_in[8];
    const float* fcW  = (const float*)d_in[9];
    const float* fcB  = (const float*)d_in[10];
    float* out = (float*)d_out;

    const int B = in_sizes[0] / SEQ;     // 2048
    seq2seq_kernel<<<B / MB, 64, 0, stream>>>(src, eWih, eWhh, eBih, eBhh,
                                              dWih, dWhh, dBih, dBhh,
                                              fcW, fcB, out);
}

// Round 6
// 564.901 us; speedup vs baseline: 1.5809x; 1.0475x over previous
//
#include <hip/hip_runtime.h>

// Seq2Seq LSTM (enc 512 + dec 256 steps), H=50, B=2048, in/out dim 1.
//
// Round-18: r17 host (barrier-free 1-wave blocks, fp16 MFMA, h fp16-split)
// with the serial step-chain shortened at the SOURCE level:
//  (a) STAGE-MAJOR activation: all 16 gate-sums, then 16 exp2, then 16
//      rcp, then 4 cc-fma + 4 exp2 + 4 rcp, then pack/write. r17 emitted
//      4 sequential full cell pipelines; if unscheduled that is 4x the
//      trans-latency depth (~800 cyc). Stage-major pays it ~once.
//  (b) PERMUTED h layout: h stored at pos pi(u)= (u&15)*4 + (u>>4), so a
//      lane's 4 cells are contiguous -> 8 scattered 2B ds_writes become
//      2 ds_write_b64. Weight k-order permuted at load to match (exact).
//  (c) srcT[b][t] + one float2 read per 2-step pair (shorter DS FIFO).
// Math identical to r17 (absmax 4.88e-4): fp16 weights (rel 2^-11),
// fp16-split h via A-rows (m = b*4 + s*2 + d), combine acc[0]+acc[2],
// L2E folded into weights/bias (g-gate doubled -> tanh via sigm).
//
// Fragment maps (verified r10-r17): A[m=lane&15][k=(lane>>4)*8+j],
// B[n=lane&15][k=kt*32+(lane>>4)*8+j], D col=lane&15, row=4*(lane>>4)+reg.

#define HID 50
#define SEQ 512
#define TGT 256
#define MB  4
#define NT  16                   // 4 gates x 4 unit-groups
#define L2E 1.44269504088896341f

typedef __attribute__((ext_vector_type(8))) _Float16 half8;
typedef __attribute__((ext_vector_type(4))) _Float16 half4;
typedef __attribute__((ext_vector_type(4))) float f32x4;

#define MFMA16(A, B, C) __builtin_amdgcn_mfma_f32_16x16x32_f16((A), (B), (C), 0, 0, 0)

// One step, stage-major. XV = x scalar for this lane's batch kg (enters at
// the sum stage, post-MFMA -> decoder feedback stays off the gemv path).
// Reads h from hs[IB], writes h' to hs[OB] (2 x ds_write_b64). hv[4]/cc[4].
#define GSTEP(XV, IB, OB)                                                   \
    {                                                                       \
        const _Float16* hp_ = &hs[IB][as][ab][0];                           \
        half8 a0 = *(const half8*)(hp_ + kg * 8);        /* pos 0..31  */   \
        half8 a1 = *(const half8*)(hp_ + 32 + kg * 8);   /* pos 32..63 */   \
        f32x4 acc[NT];                                                      \
        _Pragma("unroll")                                                   \
        for (int j = 0; j < NT; ++j) {                                      \
            f32x4 z = {0.0f, 0.0f, 0.0f, 0.0f};                             \
            z = MFMA16(a0, Bw[j][0], z);                                    \
            z = MFMA16(a1, Bw[j][1], z);                                    \
            acc[j] = z;                                                     \
        }                                                                   \
        float xv_ = (XV);                                                   \
        float s_[NT], E_[NT], R_[NT];                                       \
        _Pragma("unroll")                                                   \
        for (int j = 0; j < NT; ++j)                                        \
            s_[j] = acc[j][0] + acc[j][2] + fmaf(wx[j], xv_, bb[j]);        \
        _Pragma("unroll")                                                   \
        for (int j = 0; j < NT; ++j)                                        \
            E_[j] = __builtin_amdgcn_exp2f(-s_[j]);                         \
        _Pragma("unroll")                                                   \
        for (int j = 0; j < NT; ++j)                                        \
            R_[j] = __builtin_amdgcn_rcpf(1.0f + E_[j]);                    \
        float e2_[4], r2_[4];                                               \
        _Pragma("unroll")                                                   \
        for (int ug = 0; ug < 4; ++ug) {     /* i=R[ug] f=R[4+] g=R[8+] */  \
            float vg = fmaf(2.0f, R_[8 + ug], -1.0f);                       \
            cc[ug] = fmaf(R_[4 + ug], cc[ug], R_[ug] * vg);                 \
            e2_[ug] = __builtin_amdgcn_exp2f(-2.0f * L2E * cc[ug]);         \
        }                                                                   \
        _Pragma("unroll")                                                   \
        for (int ug = 0; ug < 4; ++ug)                                      \
            r2_[ug] = __builtin_amdgcn_rcpf(1.0f + e2_[ug]);                \
        half4 w0_, w1_;                                                     \
        _Pragma("unroll")                                                   \
        for (int ug = 0; ug < 4; ++ug) {     /* o = R[12+ug] */             \
            hv[ug] = R_[12 + ug] * fmaf(2.0f, r2_[ug], -1.0f);              \
            _Float16 q0 = (_Float16)hv[ug];                                 \
            w0_[ug] = q0;                                                   \
            w1_[ug] = (_Float16)(hv[ug] - (float)q0);                       \
        }                                                                   \
        *(half4*)&hs[OB][0][kg][c * 4] = w0_;       /* split0, b64 */       \
        *(half4*)&hs[OB][1][kg][c * 4] = w1_;       /* split1, b64 */       \
    }

// Decoder step: GSTEP + in-lane fc dot + 16-lane butterfly; y -> ys, xc.
#define DSTEP(T, IB, OB)                                                    \
    {                                                                       \
        GSTEP(xc, IB, OB)                                                   \
        float p = fmaf(fcw0, hv[0],                                         \
                  fmaf(fcw1, hv[1],                                         \
                  fmaf(fcw2, hv[2], fcw3 * hv[3])));                        \
        p += __shfl_xor(p, 1, 64);                                          \
        p += __shfl_xor(p, 2, 64);                                          \
        p += __shfl_xor(p, 4, 64);                                          \
        p += __shfl_xor(p, 8, 64);                                          \
        float y = p + fb;                                                   \
        if (c == 0) ys[kg][T] = y;                                          \
        xc = y;                                                             \
    }

extern "C" __global__ void __launch_bounds__(64, 1)
seq2seq_kernel(const float* __restrict__ src,
               const float* __restrict__ eWih, const float* __restrict__ eWhh,
               const float* __restrict__ eBih, const float* __restrict__ eBhh,
               const float* __restrict__ dWih, const float* __restrict__ dWhh,
               const float* __restrict__ dBih, const float* __restrict__ dBhh,
               const float* __restrict__ fcW, const float* __restrict__ fcB,
               float* __restrict__ out) {
    const int lane = threadIdx.x & 63;
    const int c    = lane & 15;          // D col: unit-in-group; A row m
    const int kg   = lane >> 4;          // A/B k-octet AND D batch group
    const int ab   = c >> 2;             // A-row m -> source batch
    const int as   = (c >> 1) & 1;       // A-row m -> source h-split
    const int b0   = blockIdx.x * MB;

    // hs[buf][split][batch][64 pos]; pos p holds unit (p&3)*16 + (p>>2)
    __shared__ __align__(16) _Float16 hs[2][2][MB][64];
    __shared__ __align__(16) float srcT[MB][SEQ];          // [batch][t]
    __shared__ __align__(16) float ys[MB][TGT];            // decoder outputs

    for (int i = lane; i < 2 * 2 * MB * 64 / 2; i += 64) ((int*)hs)[i] = 0;
    for (int i = lane; i < SEQ * MB; i += 64) {
        int e = i >> 9, t = i & 511;                       // coalesced in t
        srcT[e][t] = src[(size_t)(b0 + e) * SEQ + t];
    }
    // single wave: DS pipe is in-order; no barrier needed anywhere

    half8 Bw[NT][2];                     // [tile=(g*4+ug)][kt] fp16 weights
    float wx[NT], bb[NT];
    float cc[4] = {0.0f, 0.0f, 0.0f, 0.0f};
    float hv[4];

    auto loadW = [&](const float* Wih, const float* Whh,
                     const float* Bih, const float* Bhh) {
#pragma unroll
        for (int j = 0; j < NT; ++j) {
            const int g  = j >> 2, ug = j & 3;             // tile=(gate,ug)
            const int u  = ug * 16 + c;                    // output unit
            const bool uv = (u < HID);
            const float sc = (g == 2) ? 2.0f * L2E : L2E;  // tanh fold
            const int row = g * HID + (uv ? u : 0);        // PyTorch g*50+u
            wx[j] = uv ? Wih[row] * sc : 0.0f;
            bb[j] = uv ? (Bih[row] + Bhh[row]) * sc : 0.0f;
#pragma unroll
            for (int kt = 0; kt < 2; ++kt) {
                half8 s0;
#pragma unroll
                for (int jj = 0; jj < 8; ++jj) {
                    int kk = kt * 32 + kg * 8 + jj;        // k = pos index
                    int us = (kk & 3) * 16 + (kk >> 2);    // unit at pos kk
                    float wv = (uv && us < HID)
                             ? Whh[(size_t)row * HID + us] * sc : 0.0f;
                    s0[jj] = (_Float16)wv;
                }
                Bw[j][kt] = s0;
            }
        }
    };

    // ---------------- encoder: 512 steps (x2 unroll, h dbuf) -------------
    loadW(eWih, eWhh, eBih, eBhh);
    for (int t = 0; t < SEQ; t += 2) {
        float2 xp = *(const float2*)&srcT[kg][t];
        { GSTEP(xp.x, 0, 1) }
        { GSTEP(xp.y, 1, 0) }
    }
    // h(512) in buf 0; cc persists in registers

    // ---------------- decoder: 256 steps (x2 unroll) ---------------------
    loadW(dWih, dWhh, dBih, dBhh);
    const float fcw0 = fcW[c];
    const float fcw1 = fcW[16 + c];
    const float fcw2 = fcW[32 + c];
    const float fcw3 = (48 + c < HID) ? fcW[48 + c] : 0.0f;
    const float fb   = fcB[0];
    float xc = 0.0f;                     // decoder_input = zeros
    for (int t = 0; t < TGT; t += 2) {
        DSTEP(t,     0, 1)
        DSTEP(t + 1, 1, 0)
    }

    // coalesced output write
    for (int i = lane; i < MB * TGT; i += 64) {
        int b = i >> 8, t = i & 255;
        out[(size_t)(b0 + b) * TGT + t] = ys[b][t];
    }
}

extern "C" void kernel_launch(void* const* d_in, const int* in_sizes, int n_in,
                              void* d_out, int out_size, void* d_ws, size_t ws_size,
                              hipStream_t stream) {
    const float* src  = (const float*)d_in[0];
    const float* eWih = (const float*)d_in[1];
    const float* eWhh = (const float*)d_in[2];
    const float* eBih = (const float*)d_in[3];
    const float* eBhh = (const float*)d_in[4];
    const float* dWih = (const float*)d_in[5];
    const float* dWhh = (const float*)d_in[6];
    const float* dBih = (const float*)d_in[7];
    const float* dBhh = (const float*)d_in[8];
    const float* fcW  = (const float*)d_in[9];
    const float* fcB  = (const float*)d_in[10];
    float* out = (float*)d_out;

    const int B = in_sizes[0] / SEQ;     // 2048
    seq2seq_kernel<<<B / MB, 64, 0, stream>>>(src, eWih, eWhh, eBih, eBhh,
                                              dWih, dWhh, dBih, dBhh,
                                              fcW, fcB, out);
}